// Round 1
// baseline (609.189 us; speedup 1.0000x reference)
//
#include <hip/hip_runtime.h>
#include <cstdint>
#include <cstddef>

typedef short s16x8 __attribute__((ext_vector_type(8)));
typedef float f32x4 __attribute__((ext_vector_type(4)));
typedef unsigned short u16;

// ---------- fp32 -> bf16 (RNE) ----------
static __device__ __forceinline__ u16 f2bf(float f) {
  union { float f; unsigned u; } c; c.f = f;
  unsigned u = c.u;
  u += 0x7FFFu + ((u >> 16) & 1u);
  return (u16)(u >> 16);
}

// x: fp32 -> bf16, 8 elems/thread, exact-grid (M*K divisible by 2048)
__global__ __launch_bounds__(256) void cvt_x_kernel(const float* __restrict__ x,
                                                    u16* __restrict__ o) {
  const size_t i = (size_t)blockIdx.x * 256 + threadIdx.x;
  const float4* __restrict__ xv = (const float4*)x;
  float4 a = xv[i * 2];
  float4 b = xv[i * 2 + 1];
  union { u16 h[8]; int4 v; } r;
  r.h[0] = f2bf(a.x); r.h[1] = f2bf(a.y); r.h[2] = f2bf(a.z); r.h[3] = f2bf(a.w);
  r.h[4] = f2bf(b.x); r.h[5] = f2bf(b.y); r.h[6] = f2bf(b.z); r.h[7] = f2bf(b.w);
  ((int4*)o)[i] = r.v;
}

// w: int32 (values in [-127,127]) -> bf16 (exact), 8 elems/thread
__global__ __launch_bounds__(256) void cvt_w_kernel(const int* __restrict__ w,
                                                    u16* __restrict__ o) {
  const size_t i = (size_t)blockIdx.x * 256 + threadIdx.x;
  const int4* __restrict__ wv = (const int4*)w;
  int4 a = wv[i * 2];
  int4 b = wv[i * 2 + 1];
  union { u16 h[8]; int4 v; } r;
  r.h[0] = f2bf((float)a.x); r.h[1] = f2bf((float)a.y);
  r.h[2] = f2bf((float)a.z); r.h[3] = f2bf((float)a.w);
  r.h[4] = f2bf((float)b.x); r.h[5] = f2bf((float)b.y);
  r.h[6] = f2bf((float)b.z); r.h[7] = f2bf((float)b.w);
  ((int4*)o)[i] = r.v;
}

// ---------- async global->LDS, 16B per lane, wave-uniform LDS base ----------
static __device__ __forceinline__ void gld_lds16(const void* g, void* l) {
  __builtin_amdgcn_global_load_lds(
      (const __attribute__((address_space(1))) unsigned int*)g,
      (__attribute__((address_space(3))) unsigned int*)l,
      16, 0, 0);
}

// ---------- bf16 NT GEMM: C[m][n] = scaler[n] * sum_k A[m][k]*B[n][k] ----------
// block = 256 thr (4 waves), tile 128x128, BK=32. LDS 2x8KB, unpadded
// row-major [128][32] (required by global_load_lds lane scatter).
__global__ __launch_bounds__(256) void gemm_bt_kernel(
    const u16* __restrict__ A,      // [M,K] bf16
    const u16* __restrict__ B,      // [N,K] bf16
    const float* __restrict__ scaler,
    float* __restrict__ C,          // [M,N] fp32
    int M, int N, int K) {
  __shared__ __align__(16) u16 As[128 * 32];
  __shared__ __align__(16) u16 Bs[128 * 32];

  const int tid  = threadIdx.x;
  const int lane = tid & 63;
  const int wave = tid >> 6;
  const int wm   = wave >> 1;     // wave row (0..1) -> 64 rows of M
  const int wn   = wave & 1;      // wave col (0..1) -> 64 cols of N
  const int q    = lane >> 4;     // quad 0..3
  const int r16  = lane & 15;

  const int m0 = blockIdx.y * 128;
  const int n0 = blockIdx.x * 128;

  f32x4 acc[4][4];
#pragma unroll
  for (int i = 0; i < 4; ++i)
#pragma unroll
    for (int j = 0; j < 4; ++j) acc[i][j] = (f32x4){0.f, 0.f, 0.f, 0.f};

  // staging: 512 chunks of 16B per tile; chunk c -> row c>>2, 16B-subcol c&3.
  // thread t handles chunks t and t+256; LDS dst offset = chunk*16 (==row-major).
  const int  crow = tid >> 2;            // 0..63
  const int  ccol = (tid & 3) * 16;      // byte offset in row
  const size_t rsA = (size_t)K * 2;      // row stride bytes
  const char* Ag = (const char*)A + ((size_t)m0 + crow) * rsA + ccol;
  const char* Bg = (const char*)B + ((size_t)n0 + crow) * rsA + ccol;
  const size_t half = 64 * rsA;          // +64 rows

  char* AsW = (char*)As + wave * 1024;   // wave-uniform LDS bases
  char* BsW = (char*)Bs + wave * 1024;

  // LDS read offsets (elements): row-major [128][32]
  const int aoff = (wm * 64 + r16) * 32 + q * 8;
  const int boff = (wn * 64 + r16) * 32 + q * 8;

  for (int k0 = 0; k0 < K; k0 += 32) {
    const size_t kb = (size_t)k0 * 2;
    gld_lds16(Ag + kb,        AsW);
    gld_lds16(Ag + kb + half, AsW + 4096);
    gld_lds16(Bg + kb,        BsW);
    gld_lds16(Bg + kb + half, BsW + 4096);
    __syncthreads();   // drains vmcnt -> tiles visible

    s16x8 af[4], bfr[4];
#pragma unroll
    for (int mt = 0; mt < 4; ++mt)
      af[mt] = *(const s16x8*)(As + aoff + mt * (16 * 32));
#pragma unroll
    for (int nt = 0; nt < 4; ++nt)
      bfr[nt] = *(const s16x8*)(Bs + boff + nt * (16 * 32));
#pragma unroll
    for (int mt = 0; mt < 4; ++mt)
#pragma unroll
      for (int nt = 0; nt < 4; ++nt)
        acc[mt][nt] = __builtin_amdgcn_mfma_f32_16x16x32_bf16(
            af[mt], bfr[nt], acc[mt][nt], 0, 0, 0);
    __syncthreads();   // protect LDS before next overwrite
  }

  // epilogue: C/D layout col=lane&15, row=(lane>>4)*4+reg; scale by scaler[n]
#pragma unroll
  for (int nt = 0; nt < 4; ++nt) {
    const int col = n0 + wn * 64 + nt * 16 + r16;
    const float s = scaler[col];
#pragma unroll
    for (int mt = 0; mt < 4; ++mt) {
      const int row0 = m0 + wm * 64 + mt * 16 + q * 4;
      float* Cp = C + (size_t)row0 * N + col;
#pragma unroll
      for (int r = 0; r < 4; ++r)
        Cp[(size_t)r * N] = acc[mt][nt][r] * s;
    }
  }
}

// ---------- fallback (only if ws too small / odd shape) ----------
__global__ void naive_kernel(const float* __restrict__ x, const int* __restrict__ w,
                             const float* __restrict__ sc, float* __restrict__ out,
                             int M, int N, int K) {
  int idx = blockIdx.x * 256 + threadIdx.x;
  if (idx >= M * N) return;
  int m = idx / N, n = idx % N;
  const float* xr = x + (size_t)m * K;
  const int*   wr = w + (size_t)n * K;
  float acc = 0.f;
  for (int k = 0; k < K; ++k) acc += xr[k] * (float)wr[k];
  out[idx] = acc * sc[n];
}

extern "C" void kernel_launch(void* const* d_in, const int* in_sizes, int n_in,
                              void* d_out, int out_size, void* d_ws, size_t ws_size,
                              hipStream_t stream) {
  const float* x  = (const float*)d_in[0];
  const int*   w  = (const int*)d_in[1];
  const float* sc = (const float*)d_in[2];
  float* out = (float*)d_out;

  const int N = in_sizes[2];          // D_OUT
  const int K = in_sizes[1] / N;      // D_IN
  const int M = in_sizes[0] / K;      // B*S

  const size_t need = ((size_t)M * K + (size_t)N * K) * sizeof(u16);
  if (ws_size < need || (M % 128) || (N % 128) || (K % 32)) {
    int total = M * N;
    naive_kernel<<<(total + 255) / 256, 256, 0, stream>>>(x, w, sc, out, M, N, K);
    return;
  }

  u16* xb = (u16*)d_ws;
  u16* wb = xb + (size_t)M * K;

  const int xblocks = (int)(((size_t)M * K) / 2048);  // 8 elems * 256 thr
  const int wblocks = (int)(((size_t)N * K) / 2048);
  cvt_x_kernel<<<xblocks, 256, 0, stream>>>(x, xb);
  cvt_w_kernel<<<wblocks, 256, 0, stream>>>(w, wb);

  dim3 grid(N / 128, M / 128);
  gemm_bt_kernel<<<grid, 256, 0, stream>>>(xb, wb, sc, out, M, N, K);
}

// Round 2
// 605.351 us; speedup vs baseline: 1.0063x; 1.0063x over previous
//
#include <hip/hip_runtime.h>
#include <cstdint>
#include <cstddef>

typedef short s16x8 __attribute__((ext_vector_type(8)));
typedef float f32x4 __attribute__((ext_vector_type(4)));
typedef unsigned short u16;

// ---------- fp32 -> bf16 (RNE) ----------
static __device__ __forceinline__ u16 f2bf(float f) {
  union { float f; unsigned u; } c; c.f = f;
  unsigned u = c.u;
  u += 0x7FFFu + ((u >> 16) & 1u);
  return (u16)(u >> 16);
}

// Fused convert: one launch covers both tensors.
//  blocks [0, xblocks)          : x fp32 -> bf16   (4 elems/thread, float4 in, short4 out)
//  blocks [xblocks, xblocks+wb) : w int32 -> bf16  (4 elems/thread, int4 in, short4 out)
// Perfect coalescing: thread i loads 16B at i*16, stores 8B at i*8.
__global__ __launch_bounds__(256) void cvt_all_kernel(
    const float* __restrict__ x, u16* __restrict__ xo,
    const int* __restrict__ w,   u16* __restrict__ wo,
    int xblocks) {
  union { u16 h[4]; short2 s2[2]; uint2 v; } r;
  if (blockIdx.x < xblocks) {
    const size_t i = (size_t)blockIdx.x * 256 + threadIdx.x;
    float4 a = ((const float4*)x)[i];
    r.h[0] = f2bf(a.x); r.h[1] = f2bf(a.y); r.h[2] = f2bf(a.z); r.h[3] = f2bf(a.w);
    ((uint2*)xo)[i] = r.v;
  } else {
    const size_t i = (size_t)(blockIdx.x - xblocks) * 256 + threadIdx.x;
    int4 a = ((const int4*)w)[i];
    r.h[0] = f2bf((float)a.x); r.h[1] = f2bf((float)a.y);
    r.h[2] = f2bf((float)a.z); r.h[3] = f2bf((float)a.w);
    ((uint2*)wo)[i] = r.v;
  }
}

// ---------- async global->LDS, 16B per lane, wave-uniform LDS base ----------
static __device__ __forceinline__ void gld_lds16(const void* g, void* l) {
  __builtin_amdgcn_global_load_lds(
      (const __attribute__((address_space(1))) unsigned int*)g,
      (__attribute__((address_space(3))) unsigned int*)l,
      16, 0, 0);
}

// ---------- bf16 NT GEMM: C[m][n] = scaler[n] * sum_k A[m][k]*B[n][k] ----------
// block = 256 thr (4 waves), tile 128x128, BK=32. LDS 2x8KB, unpadded
// row-major [128][32] (required by global_load_lds lane scatter).
// This is the m97-ladder structure; at this shape it plateaus ~700-780 TF
// (m102 shape curve) — structural, not memory/conflict-bound (HBM 15%,
// MfmaUtil 32%, VALUBusy 45% measured R1).
__global__ __launch_bounds__(256) void gemm_bt_kernel(
    const u16* __restrict__ A,      // [M,K] bf16
    const u16* __restrict__ B,      // [N,K] bf16
    const float* __restrict__ scaler,
    float* __restrict__ C,          // [M,N] fp32
    int M, int N, int K) {
  __shared__ __align__(16) u16 As[128 * 32];
  __shared__ __align__(16) u16 Bs[128 * 32];

  const int tid  = threadIdx.x;
  const int lane = tid & 63;
  const int wave = tid >> 6;
  const int wm   = wave >> 1;     // wave row (0..1) -> 64 rows of M
  const int wn   = wave & 1;      // wave col (0..1) -> 64 cols of N
  const int q    = lane >> 4;     // quad 0..3
  const int r16  = lane & 15;

  const int m0 = blockIdx.y * 128;
  const int n0 = blockIdx.x * 128;

  f32x4 acc[4][4];
#pragma unroll
  for (int i = 0; i < 4; ++i)
#pragma unroll
    for (int j = 0; j < 4; ++j) acc[i][j] = (f32x4){0.f, 0.f, 0.f, 0.f};

  // staging: 512 chunks of 16B per tile; chunk c -> row c>>2, 16B-subcol c&3.
  const int  crow = tid >> 2;            // 0..63
  const int  ccol = (tid & 3) * 16;      // byte offset in row
  const size_t rsA = (size_t)K * 2;      // row stride bytes
  const char* Ag = (const char*)A + ((size_t)m0 + crow) * rsA + ccol;
  const char* Bg = (const char*)B + ((size_t)n0 + crow) * rsA + ccol;
  const size_t half = 64 * rsA;          // +64 rows

  char* AsW = (char*)As + wave * 1024;   // wave-uniform LDS bases
  char* BsW = (char*)Bs + wave * 1024;

  // LDS read offsets (elements): row-major [128][32]
  const int aoff = (wm * 64 + r16) * 32 + q * 8;
  const int boff = (wn * 64 + r16) * 32 + q * 8;

  for (int k0 = 0; k0 < K; k0 += 32) {
    const size_t kb = (size_t)k0 * 2;
    gld_lds16(Ag + kb,        AsW);
    gld_lds16(Ag + kb + half, AsW + 4096);
    gld_lds16(Bg + kb,        BsW);
    gld_lds16(Bg + kb + half, BsW + 4096);
    __syncthreads();   // drains vmcnt -> tiles visible

    s16x8 af[4], bfr[4];
#pragma unroll
    for (int mt = 0; mt < 4; ++mt)
      af[mt] = *(const s16x8*)(As + aoff + mt * (16 * 32));
#pragma unroll
    for (int nt = 0; nt < 4; ++nt)
      bfr[nt] = *(const s16x8*)(Bs + boff + nt * (16 * 32));
#pragma unroll
    for (int mt = 0; mt < 4; ++mt)
#pragma unroll
      for (int nt = 0; nt < 4; ++nt)
        acc[mt][nt] = __builtin_amdgcn_mfma_f32_16x16x32_bf16(
            af[mt], bfr[nt], acc[mt][nt], 0, 0, 0);
    __syncthreads();   // protect LDS before next overwrite
  }

  // epilogue: C/D layout col=lane&15, row=(lane>>4)*4+reg; scale by scaler[n]
#pragma unroll
  for (int nt = 0; nt < 4; ++nt) {
    const int col = n0 + wn * 64 + nt * 16 + r16;
    const float s = scaler[col];
#pragma unroll
    for (int mt = 0; mt < 4; ++mt) {
      const int row0 = m0 + wm * 64 + mt * 16 + q * 4;
      float* Cp = C + (size_t)row0 * N + col;
#pragma unroll
      for (int r = 0; r < 4; ++r)
        Cp[(size_t)r * N] = acc[mt][nt][r] * s;
    }
  }
}

// ---------- fallback (only if ws too small / odd shape) ----------
__global__ void naive_kernel(const float* __restrict__ x, const int* __restrict__ w,
                             const float* __restrict__ sc, float* __restrict__ out,
                             int M, int N, int K) {
  int idx = blockIdx.x * 256 + threadIdx.x;
  if (idx >= M * N) return;
  int m = idx / N, n = idx % N;
  const float* xr = x + (size_t)m * K;
  const int*   wr = w + (size_t)n * K;
  float acc = 0.f;
  for (int k = 0; k < K; ++k) acc += xr[k] * (float)wr[k];
  out[idx] = acc * sc[n];
}

extern "C" void kernel_launch(void* const* d_in, const int* in_sizes, int n_in,
                              void* d_out, int out_size, void* d_ws, size_t ws_size,
                              hipStream_t stream) {
  const float* x  = (const float*)d_in[0];
  const int*   w  = (const int*)d_in[1];
  const float* sc = (const float*)d_in[2];
  float* out = (float*)d_out;

  const int N = in_sizes[2];          // D_OUT
  const int K = in_sizes[1] / N;      // D_IN
  const int M = in_sizes[0] / K;      // B*S

  const size_t need = ((size_t)M * K + (size_t)N * K) * sizeof(u16);
  if (ws_size < need || (M % 128) || (N % 128) || (K % 32) ||
      (((size_t)M * K) % 1024) || (((size_t)N * K) % 1024)) {
    int total = M * N;
    naive_kernel<<<(total + 255) / 256, 256, 0, stream>>>(x, w, sc, out, M, N, K);
    return;
  }

  u16* xb = (u16*)d_ws;
  u16* wb = xb + (size_t)M * K;

  // one fused convert launch: 4 elems/thread, 1024 elems/block
  const int xblocks = (int)(((size_t)M * K) / 1024);
  const int wblocks = (int)(((size_t)N * K) / 1024);
  cvt_all_kernel<<<xblocks + wblocks, 256, 0, stream>>>(x, xb, w, wb, xblocks);

  dim3 grid(N / 128, M / 128);
  gemm_bt_kernel<<<grid, 256, 0, stream>>>(xb, wb, sc, out, M, N, K);
}